// Round 3
// baseline (4824.575 us; speedup 1.0000x reference)
//
#include <hip/hip_runtime.h>

#define DEV __device__ __forceinline__

typedef __bf16 bf16x8 __attribute__((ext_vector_type(8)));
typedef float f32x4 __attribute__((ext_vector_type(4)));

DEV unsigned short f2bf(float f) {
    unsigned u = __builtin_bit_cast(unsigned, f);
    u += 0x7fffu + ((u >> 16) & 1u);   // round-to-nearest-even
    return (unsigned short)(u >> 16);
}

// Detect whether edge_index buffer is int64-layout (odd 32-bit words all zero,
// since node ids < 50000) or int32. Writes 1 for int64-layout, 0 for int32.
__global__ void detect_kernel(const int* __restrict__ ei, int* __restrict__ flag)
{
    if (threadIdx.x == 0 && blockIdx.x == 0) {
        int z = 1;
        for (int i = 1; i < 64; i += 2) z &= (ei[i] == 0);
        *flag = z;
    }
}

// t = x (f32 copy); zero the 512 stat floats
__global__ __launch_bounds__(256) void init_kernel(
    const float* __restrict__ xin, float* __restrict__ t,
    float* __restrict__ stats, int nv4)
{
    int g = blockIdx.x * 256 + threadIdx.x;
    if (g < 512) stats[g] = 0.f;
    if (g < nv4) {
        *(float4*)(t + (size_t)g * 4) = *(const float4*)(xin + (size_t)g * 4);
    }
}

// per edge: t[dst] += relu(x[src] + edge_attr[e]); 32 lanes/edge, 4 dims/lane
__global__ __launch_bounds__(256) void edge_kernel(
    const float* __restrict__ x, const float* __restrict__ ea,
    const int* __restrict__ ei, const int* __restrict__ i64flag,
    float* __restrict__ t, int E)
{
    int g = blockIdx.x * 256 + threadIdx.x;
    int e = g >> 5;
    if (e >= E) return;
    int d0 = (g & 31) * 4;
    int s, d;
    if (*i64flag) {  // int64 layout: low word of each 8-byte entry
        s = ei[2 * (size_t)e];
        d = ei[2 * (size_t)E + 2 * (size_t)e];
    } else {         // int32 layout
        s = ei[e];
        d = ei[(size_t)E + e];
    }
    float4 xv = *(const float4*)(x + (size_t)s * 128 + d0);
    float4 av = *(const float4*)(ea + (size_t)e * 128 + d0);
    float m0 = fmaxf(xv.x + av.x, 0.f);
    float m1 = fmaxf(xv.y + av.y, 0.f);
    float m2 = fmaxf(xv.z + av.z, 0.f);
    float m3 = fmaxf(xv.w + av.w, 0.f);
    float* ap = t + (size_t)d * 128 + d0;
    atomicAdd(ap + 0, m0); atomicAdd(ap + 1, m1);
    atomicAdd(ap + 2, m2); atomicAdd(ap + 3, m3);
}

// out[n][c] = sum_k in[n][k]*W[k][c] + bias[c]; f32 in/out, bf16 MFMA inside.
// Block = 64 rows x 128 cols, 4 waves. Each block stages its 64 rows to LDS
// before writing, so in-place (out == in) is safe.
__global__ __launch_bounds__(256) void gemm_kernel(
    const float* __restrict__ inp,
    const float* __restrict__ W,     // [128][128] f32, [k][c]
    const float* __restrict__ bias,  // [128] f32
    float* __restrict__ out, int N)
{
    __shared__ __attribute__((aligned(16))) unsigned short As[64][136];   // [r][k]
    __shared__ __attribute__((aligned(16))) unsigned short Ws[128][136];  // [c][k] (transposed)
    const int tid = threadIdx.x;
    const int row0 = blockIdx.x * 64;

    // stage W transposed as bf16: Ws[c][k] = W[k*128+c]
#pragma unroll
    for (int it = 0; it < 8; ++it) {
        int lin = (it * 256 + tid) * 8;
        int k = lin >> 7;
        int c = lin & 127;
        const float* wp = W + (size_t)k * 128 + c;
        float4 wa = *(const float4*)wp;
        float4 wb = *(const float4*)(wp + 4);
        Ws[c + 0][k] = f2bf(wa.x); Ws[c + 1][k] = f2bf(wa.y);
        Ws[c + 2][k] = f2bf(wa.z); Ws[c + 3][k] = f2bf(wa.w);
        Ws[c + 4][k] = f2bf(wb.x); Ws[c + 5][k] = f2bf(wb.y);
        Ws[c + 6][k] = f2bf(wb.z); Ws[c + 7][k] = f2bf(wb.w);
    }
    // stage A tile as bf16 (zero-pad tail rows)
#pragma unroll
    for (int it = 0; it < 8; ++it) {
        int lin = (it * 256 + tid) * 4;
        int r = lin >> 7;
        int c = lin & 127;
        int row = row0 + r;
        if (row < N) {
            float4 v = *(const float4*)(inp + (size_t)row * 128 + c);
            As[r][c + 0] = f2bf(v.x); As[r][c + 1] = f2bf(v.y);
            As[r][c + 2] = f2bf(v.z); As[r][c + 3] = f2bf(v.w);
        } else {
            As[r][c + 0] = 0; As[r][c + 1] = 0; As[r][c + 2] = 0; As[r][c + 3] = 0;
        }
    }
    __syncthreads();

    const int wave = tid >> 6;
    const int lane = tid & 63;
    const int quad = lane >> 4;
    const int m16  = lane & 15;

    // A fragments: A[m=lane&15][k=quad*8+j], 8 contiguous bf16 -> ds_read_b128
    bf16x8 af[4];
#pragma unroll
    for (int kk = 0; kk < 4; ++kk)
        af[kk] = *reinterpret_cast<const bf16x8*>(&As[wave * 16 + m16][kk * 32 + quad * 8]);

#pragma unroll
    for (int ct = 0; ct < 8; ++ct) {
        f32x4 acc = {0.f, 0.f, 0.f, 0.f};
#pragma unroll
        for (int kk = 0; kk < 4; ++kk) {
            // B fragment: B[k=quad*8+j][n=lane&15] = Ws[n][k], contiguous in k
            bf16x8 bf = *reinterpret_cast<const bf16x8*>(&Ws[ct * 16 + m16][kk * 32 + quad * 8]);
            acc = __builtin_amdgcn_mfma_f32_16x16x32_bf16(af[kk], bf, acc, 0, 0, 0);
        }
        int col = ct * 16 + m16;
        float bb = bias[col];
#pragma unroll
        for (int r = 0; r < 4; ++r) {
            int row = row0 + wave * 16 + quad * 4 + r;  // C/D: row = quad*4+reg, col = lane&15
            if (row < N) out[(size_t)row * 128 + col] = acc[r] + bb;
        }
    }
}

// column sums / sums-of-squares over N rows
__global__ __launch_bounds__(256) void stats_kernel(
    const float* __restrict__ t, float* __restrict__ sum, float* __restrict__ sq, int N)
{
    __shared__ float ss[128], qq[128];
    int tid = threadIdx.x;
    if (tid < 128) { ss[tid] = 0.f; qq[tid] = 0.f; }
    __syncthreads();
    int g = blockIdx.x * 256 + tid;
    int c4 = (g & 31) * 4;
    int r = g >> 5;
    int rstride = (gridDim.x * 256) >> 5;
    float s0 = 0, s1 = 0, s2 = 0, s3 = 0, q0 = 0, q1 = 0, q2 = 0, q3 = 0;
    for (; r < N; r += rstride) {
        float4 v = *(const float4*)(t + (size_t)r * 128 + c4);
        s0 += v.x; q0 += v.x * v.x;
        s1 += v.y; q1 += v.y * v.y;
        s2 += v.z; q2 += v.z * v.z;
        s3 += v.w; q3 += v.w * v.w;
    }
    atomicAdd(&ss[c4 + 0], s0); atomicAdd(&qq[c4 + 0], q0);
    atomicAdd(&ss[c4 + 1], s1); atomicAdd(&qq[c4 + 1], q1);
    atomicAdd(&ss[c4 + 2], s2); atomicAdd(&qq[c4 + 2], q2);
    atomicAdd(&ss[c4 + 3], s3); atomicAdd(&qq[c4 + 3], q3);
    __syncthreads();
    if (tid < 128) { atomicAdd(&sum[tid], ss[tid]); atomicAdd(&sq[tid], qq[tid]); }
}

// out = [relu?] (gamma * (t - mean) * rsqrt(var + eps) + beta), f32 out
__global__ __launch_bounds__(256) void bn_kernel(
    const float* __restrict__ t, const float* __restrict__ sum, const float* __restrict__ sq,
    const float* __restrict__ gamma, const float* __restrict__ beta,
    float* __restrict__ out, int N, int do_relu, int nv4)
{
    __shared__ float sc[128], sh[128];
    int tid = threadIdx.x;
    if (tid < 128) {
        float inv = 1.f / (float)N;
        float m = sum[tid] * inv;
        float v = sq[tid] * inv - m * m;
        v = fmaxf(v, 0.f);
        float rs = rsqrtf(v + 1e-5f);
        float gr = gamma[tid] * rs;
        sc[tid] = gr;
        sh[tid] = beta[tid] - m * gr;
    }
    __syncthreads();
    int g = blockIdx.x * 256 + tid;
    if (g < nv4) {
        int c = (g & 31) * 4;
        float4 v = *(const float4*)(t + (size_t)g * 4);
        float4 o;
        o.x = v.x * sc[c + 0] + sh[c + 0];
        o.y = v.y * sc[c + 1] + sh[c + 1];
        o.z = v.z * sc[c + 2] + sh[c + 2];
        o.w = v.w * sc[c + 3] + sh[c + 3];
        if (do_relu) {
            o.x = fmaxf(o.x, 0.f); o.y = fmaxf(o.y, 0.f);
            o.z = fmaxf(o.z, 0.f); o.w = fmaxf(o.w, 0.f);
        }
        *(float4*)(out + (size_t)g * 4) = o;
    }
}

extern "C" void kernel_launch(void* const* d_in, const int* in_sizes, int n_in,
                              void* d_out, int out_size, void* d_ws, size_t ws_size,
                              hipStream_t stream)
{
    const float* x  = (const float*)d_in[0];
    const int* ei   = (const int*)d_in[1];
    const float* ea = (const float*)d_in[2];
    // d_in[3] = batch (unused)
    const float* W1 = (const float*)d_in[4];
    const float* b1 = (const float*)d_in[5];
    const float* gm = (const float*)d_in[6];
    const float* bm = (const float*)d_in[7];
    const float* W2 = (const float*)d_in[8];
    const float* b2 = (const float*)d_in[9];
    const float* go = (const float*)d_in[10];
    const float* bo = (const float*)d_in[11];
    float* out = (float*)d_out;

    const int N = in_sizes[0] / 128;   // 50000
    const int E = in_sizes[2] / 128;   // 800000

    char* w = (char*)d_ws;
    float* t    = (float*)w;   w += (size_t)N * 128 * 4;   // aggr & gemm buf (in-place)
    float* xbuf = (float*)w;   w += (size_t)N * 128 * 4;   // inter-layer x
    float* hbuf = (float*)w;   w += (size_t)N * 128 * 4;   // post-BN1 activations
    float* stats = (float*)w;  w += 512 * 4;
    int* i64flag = (int*)w;

    const int nv4 = N * 32;
    const int gElem = (nv4 + 255) / 256;
    const int gEdge = (E * 32 + 255) / 256;
    const int gGemm = (N + 63) / 64;

    detect_kernel<<<1, 64, 0, stream>>>(ei, i64flag);

    for (int i = 0; i < 3; ++i) {
        const float* xin = (i == 0) ? x : xbuf;
        float* xout = (i == 2) ? out : xbuf;

        init_kernel<<<gElem, 256, 0, stream>>>(xin, t, stats, nv4);
        edge_kernel<<<gEdge, 256, 0, stream>>>(xin, ea, ei, i64flag, t, E);
        gemm_kernel<<<gGemm, 256, 0, stream>>>(t, W1 + (size_t)i * 16384, b1 + i * 128, t, N);
        stats_kernel<<<256, 256, 0, stream>>>(t, stats, stats + 128, N);
        bn_kernel<<<gElem, 256, 0, stream>>>(t, stats, stats + 128, gm + i * 128, bm + i * 128,
                                             hbuf, N, 1, nv4);
        gemm_kernel<<<gGemm, 256, 0, stream>>>(hbuf, W2 + (size_t)i * 16384, b2 + i * 128, t, N);
        stats_kernel<<<256, 256, 0, stream>>>(t, stats + 256, stats + 384, N);
        bn_kernel<<<gElem, 256, 0, stream>>>(t, stats + 256, stats + 384, go + i * 128, bo + i * 128,
                                             xout, N, (i < 2) ? 1 : 0, nv4);
    }
}